// Round 4
// baseline (1950.718 us; speedup 1.0000x reference)
//
#include <hip/hip_runtime.h>
#include <hip/hip_bf16.h>
#include <stdint.h>
#include <math.h>

// TreeLSTM on MI355X — v4: padded row-major LDS A tile (nt-staged), packed-B
// fragments with 2-deep register prefetch, nt streaming loads to protect L2.
//  - xg = emb[ids] @ W collapses to a 4x64x256 table (V=64).
//  - [hl|hr] A-matrix is h_prev reinterpreted as (B*n, 512): zero movement.
//  - Block = 4 waves x 64 shared rows; wave w does col-tiles 4w..4w+3.
//  - A tile 64x512 bf16 in LDS, row stride 520 (+16B pad): ds_write/ds_read
//    both canonical-conflict-free. A read from HBM exactly once per level.
//  - B pre-packed in fragment order (1.25MB, L2-resident): dense 1KB loads.
//  - Streaming traffic (A stage, Cprev) uses nontemporal loads so BtP + xg
//    stay L2-resident (v3's 333MB FETCH was BtP thrashing to L3/HBM).

typedef __bf16 bf16x8 __attribute__((ext_vector_type(8)));
typedef float  f32x4  __attribute__((ext_vector_type(4)));
typedef int    i32x4  __attribute__((ext_vector_type(4)));

__device__ __forceinline__ float sigf(float x) { return 1.f / (1.f + __expf(-x)); }
__device__ __forceinline__ float tanhfast(float x) {
    return 1.f - 2.f / (__expf(2.f * x) + 1.f);   // stable at |x| large
}

__global__ void xg_prep(const float* __restrict__ emb, const float* __restrict__ W,
                        const float* __restrict__ bW, float* __restrict__ xg) {
    int g = blockIdx.x >> 6, v = blockIdx.x & 63, k = threadIdx.x;
    __shared__ float e[256];
    e[k] = emb[v * 256 + k];
    __syncthreads();
    float s = bW[g * 256 + k];
    const float* Wg = W + g * 65536 + k;
#pragma unroll 4
    for (int i = 0; i < 256; i++) s += e[i] * Wg[i * 256];
    xg[(g * 64 + v) * 256 + k] = s;
}

// Pack U into MFMA-fragment order: BtP[g][ct][ks][lane][e], e<8
// value = Ucat[g][col = ct*16 + (lane&15)][k = ks*32 + (lane>>4)*8 + e]
// Ucat[g][col][k] = U[g][k<256?0:1][k&255][col]
__global__ void bt_prep(const float* __restrict__ U, __bf16* __restrict__ BtP) {
    int t = blockIdx.x * 256 + threadIdx.x;     // < 81920
    int g    = t >> 14;
    int r    = t & 16383;
    int ct   = r >> 10;
    int ks   = (r >> 6) & 15;
    int lane = t & 63;
    int lr = lane & 15, q = lane >> 4;
    int col = ct * 16 + lr;
    int kbase = ks * 32 + q * 8;
    bf16x8 v8;
#pragma unroll
    for (int e = 0; e < 8; e++) {
        int k = kbase + e;
        int s = k >> 8, kk = k & 255;
        v8[e] = (__bf16)U[((g * 2 + s) * 256 + kk) * 256 + col];
    }
    *(bf16x8*)(BtP + (long)t * 8) = v8;
}

__global__ void leaf_kernel(const int* __restrict__ ids, const float* __restrict__ xg,
                            __bf16* __restrict__ h, __bf16* __restrict__ c) {
    int col = threadIdx.x;                 // 0..255
    int r0 = blockIdx.x * 32;              // 2048 blocks x 32 rows
    for (int r = r0; r < r0 + 32; r++) {
        int b = r >> 10, j = r & 1023;
        int id = ids[b * 2046 + 1022 + j];
        float x1 = xg[(64  + id) * 256 + col];
        float x2 = xg[(128 + id) * 256 + col];
        float x3 = xg[(192 + id) * 256 + col];
        float ig = sigf(x1);
        float og = sigf(x2);
        float ug = tanhfast(x3);
        float cv = ig * ug;
        float hv = og * tanhfast(cv);
        h[r * 256 + col] = (__bf16)hv;
        c[r * 256 + col] = (__bf16)cv;
    }
}

#define ASTRIDE 520   // 512 + 8 elem pad: keeps ds_read/ds_write conflict-free

// Block = 256 thr = 4 waves; tile = 64 rows; wave w covers col-tiles 4w..4w+3.
__global__ __launch_bounds__(256, 2) void level_kernel(
    const __bf16* __restrict__ A, const __bf16* __restrict__ Cprev,
    const __bf16* __restrict__ BtP, const float* __restrict__ xg,
    const int* __restrict__ ids, __bf16* __restrict__ h_out,
    __bf16* __restrict__ c_out, float* __restrict__ rh_out, int lev) {
    __shared__ __bf16 Alds[64 * ASTRIDE];  // 66560 B -> 2 blocks/CU
    const int tid  = threadIdx.x;
    const int wave = tid >> 6;
    const int lane = tid & 63;
    const int lr = lane & 15, q = lane >> 4;
    const long rowblk = (long)blockIdx.x * 64;

    // Stage A tile (64 rows x 512 bf16) -> LDS row-major (stride ASTRIDE).
    // Per instr: 4 rows x 16 chunks of 16B = 16 full 64B segments (coalesced);
    // nt so the stream doesn't evict BtP/xg from L2.
    {
        const int rr = tid >> 4;           // 0..15
        const int cc = tid & 15;           // 0..15
#pragma unroll
        for (int rb = 0; rb < 4; rb++)
#pragma unroll
            for (int cb = 0; cb < 4; cb++) {
                int row = rb * 16 + rr, chunk = cb * 16 + cc;
                i32x4 v = __builtin_nontemporal_load(
                    (const i32x4*)(A + (rowblk + row) * 512 + chunk * 8));
                *(i32x4*)(&Alds[row * ASTRIDE + chunk * 8]) = v;
            }
    }

    // Row ids are col-tile independent: hoist.
    const int n = 1 << lev;
    int idv[4][4];
#pragma unroll
    for (int mt = 0; mt < 4; mt++)
#pragma unroll
        for (int v = 0; v < 4; v++) {
            long grow = rowblk + mt * 16 + q * 4 + v;
            int b = (int)(grow >> lev);
            int j = (int)(grow & (n - 1));
            idv[mt][v] = ids[b * 2046 + (n - 2) + j];
        }

    __syncthreads();

    for (int t = 0; t < 4; t++) {
        const int ct = wave * 4 + t;
        const __bf16* Bp = BtP + (long)ct * 8192 + lane * 8;  // + g*131072 + ks*512

        f32x4 acc[5][4];
#pragma unroll
        for (int g2 = 0; g2 < 5; g2++)
#pragma unroll
            for (int mt = 0; mt < 4; mt++) acc[g2][mt] = (f32x4){0.f, 0.f, 0.f, 0.f};

        bf16x8 bb[3][5], aa[2][4];
#pragma unroll
        for (int g2 = 0; g2 < 5; g2++) {
            bb[0][g2] = *(const bf16x8*)(Bp + g2 * 131072);
            bb[1][g2] = *(const bf16x8*)(Bp + g2 * 131072 + 512);
        }
#pragma unroll
        for (int mt = 0; mt < 4; mt++)
            aa[0][mt] = *(const bf16x8*)(&Alds[(mt * 16 + lr) * ASTRIDE + q * 8]);

#pragma unroll
        for (int s = 0; s < 16; s++) {
            if (s + 2 < 16) {
#pragma unroll
                for (int g2 = 0; g2 < 5; g2++)
                    bb[(s + 2) % 3][g2] =
                        *(const bf16x8*)(Bp + g2 * 131072 + (s + 2) * 512);
            }
            if (s + 1 < 16) {
#pragma unroll
                for (int mt = 0; mt < 4; mt++)
                    aa[(s + 1) & 1][mt] = *(const bf16x8*)(
                        &Alds[(mt * 16 + lr) * ASTRIDE + (s + 1) * 32 + q * 8]);
            }
#pragma unroll
            for (int g2 = 0; g2 < 5; g2++)
#pragma unroll
                for (int mt = 0; mt < 4; mt++)
                    acc[g2][mt] = __builtin_amdgcn_mfma_f32_16x16x32_bf16(
                        aa[s & 1][mt], bb[s % 3][g2], acc[g2][mt], 0, 0, 0);
        }

        // Epilogue: in-register gate combine. C layout: col=lane&15, row=q*4+v.
        const int gcol = ct * 16 + lr;
#pragma unroll
        for (int mt = 0; mt < 4; mt++) {
#pragma unroll
            for (int v = 0; v < 4; v++) {
                long grow = rowblk + mt * 16 + q * 4 + v;
                const float* xp = xg + idv[mt][v] * 256 + gcol;
                float fl = sigf(acc[0][mt][v] + xp[0]);          // f_l,f_r share xg[0]
                float fr = sigf(acc[1][mt][v] + xp[0]);
                float ig = sigf(acc[2][mt][v] + xp[16384]);      // xg[1]
                float og = sigf(acc[3][mt][v] + xp[32768]);      // xg[2]
                float ug = tanhfast(acc[4][mt][v] + xp[49152]);  // xg[3]
                __bf16 cl16 = __builtin_nontemporal_load(&Cprev[grow * 512 + gcol]);
                __bf16 cr16 = __builtin_nontemporal_load(&Cprev[grow * 512 + 256 + gcol]);
                float cv = ig * ug + fl * (float)cl16 + fr * (float)cr16;
                float hv = og * tanhfast(cv);
                h_out[grow * 256 + gcol] = (__bf16)hv;
                c_out[grow * 256 + gcol] = (__bf16)cv;
                if (rh_out) rh_out[grow * 256 + gcol] = hv;
            }
        }
    }
}

__global__ void scores_kernel(const float* __restrict__ rh, const float* __restrict__ Ws,
                              const float* __restrict__ bs, float* __restrict__ out) {
    int b = blockIdx.x;
    int t = threadIdx.x >> 6, lane = threadIdx.x & 63;
    float s = 0.f;
    for (int i = lane; i < 512; i += 64) s += rh[b * 512 + i] * Ws[i * 3 + t];
    for (int o = 32; o > 0; o >>= 1) s += __shfl_down(s, o);
    if (lane == 0) out[b * 3 + t] = s + bs[t];
}

extern "C" void kernel_launch(void* const* d_in, const int* in_sizes, int n_in,
                              void* d_out, int out_size, void* d_ws, size_t ws_size,
                              hipStream_t stream) {
    const int*   ids = (const int*)  d_in[0];
    const float* emb = (const float*)d_in[1];
    const float* W   = (const float*)d_in[2];
    const float* bW  = (const float*)d_in[3];
    const float* U   = (const float*)d_in[4];
    const float* Ws  = (const float*)d_in[5];
    const float* bs  = (const float*)d_in[6];
    float* out = (float*)d_out;   // [0:192) scores, [192:) root_hidden (64x512)

    char* ws = (char*)d_ws;
    float*  xg  = (float*)ws;                   //   262144 B : xg_table[4][64][256]
    __bf16* BtP = (__bf16*)(ws + 262144);       //  1310720 B : packed B fragments
    __bf16* h0  = (__bf16*)(ws + 1572864);      // 33554432 B : h ping (leaf-sized)
    __bf16* c0  = (__bf16*)(ws + 35127296);     // 33554432 B
    __bf16* h1  = (__bf16*)(ws + 68681728);     // 16777216 B : h pong
    __bf16* c1  = (__bf16*)(ws + 85458944);     // 16777216 B   (total 102236160 B)

    xg_prep<<<dim3(256), dim3(256), 0, stream>>>(emb, W, bW, xg);
    bt_prep<<<dim3(320), dim3(256), 0, stream>>>(U, BtP);
    leaf_kernel<<<dim3(2048), dim3(256), 0, stream>>>(ids, xg, h0, c0);

    __bf16* hb[2] = {h0, h1};
    __bf16* cb[2] = {c0, c1};
    int cur = 0;
    for (int lev = 9; lev >= 1; lev--) {
        int M = 64 << lev;                      // B * 2^lev rows
        float* rh = (lev == 1) ? (out + 192) : nullptr;
        level_kernel<<<dim3(M / 64), dim3(256), 0, stream>>>(
            hb[cur], cb[cur], BtP, xg, ids, hb[1 - cur], cb[1 - cur], rh, lev);
        cur = 1 - cur;
    }
    scores_kernel<<<dim3(64), dim3(192), 0, stream>>>(out + 192, Ws, bs, out);
}

// Round 5
// 451.640 us; speedup vs baseline: 4.3192x; 4.3192x over previous
//
#include <hip/hip_runtime.h>
#include <hip/hip_bf16.h>
#include <stdint.h>
#include <math.h>

// TreeLSTM on MI355X — v5: v2's XCD-affine decomposition + LDS-resident B-slice
// + deep explicit prefetch.
//  - xg = emb[ids] @ W collapses to a 4x64x256 table (V=64).
//  - [hl|hr] A-matrix is h_prev reinterpreted as (B*n, 512): zero movement.
//  - Grid (M/512, 16 ct): grid.x % 8 == 0 keeps all 16 ct-slices of a row
//    group on one XCD -> A-tile reuse hits L2 (v2 measured FETCH ~= ideal).
//  - Block = 8 waves x 64 rows, one 16-col ct-slice, all 5 gates per wave.
//    B-slice (5g x 16col x 512K = 80KB) staged once into LDS in fragment
//    order; K-loop feeds MFMA from ds_read_b128 (conflict-free).
//  - A-frags from global (L2) with 3-buffer 2-step-ahead prefetch; Cprev
//    preloaded before the K-loop; epilogue = v2's measured-clean store pattern.

typedef __bf16 bf16x8 __attribute__((ext_vector_type(8)));
typedef float  f32x4  __attribute__((ext_vector_type(4)));
typedef int    i32x4  __attribute__((ext_vector_type(4)));

__device__ __forceinline__ float sigf(float x) { return 1.f / (1.f + __expf(-x)); }
__device__ __forceinline__ float tanhfast(float x) {
    return 1.f - 2.f / (__expf(2.f * x) + 1.f);   // stable at |x| large
}

__global__ void xg_prep(const float* __restrict__ emb, const float* __restrict__ W,
                        const float* __restrict__ bW, float* __restrict__ xg) {
    int g = blockIdx.x >> 6, v = blockIdx.x & 63, k = threadIdx.x;
    __shared__ float e[256];
    e[k] = emb[v * 256 + k];
    __syncthreads();
    float s = bW[g * 256 + k];
    const float* Wg = W + g * 65536 + k;
#pragma unroll 4
    for (int i = 0; i < 256; i++) s += e[i] * Wg[i * 256];
    xg[(g * 64 + v) * 256 + k] = s;
}

// Pack U into MFMA-fragment order: BtP[g][ct][ks][lane][e], e<8
// value = Ucat[g][col = ct*16 + (lane&15)][k = ks*32 + (lane>>4)*8 + e]
// Ucat[g][col][k] = U[g][k<256?0:1][k&255][col]
__global__ void bt_prep(const float* __restrict__ U, __bf16* __restrict__ BtP) {
    int t = blockIdx.x * 256 + threadIdx.x;     // < 81920
    int g    = t >> 14;
    int r    = t & 16383;
    int ct   = r >> 10;
    int ks   = (r >> 6) & 15;
    int lane = t & 63;
    int lr = lane & 15, q = lane >> 4;
    int col = ct * 16 + lr;
    int kbase = ks * 32 + q * 8;
    bf16x8 v8;
#pragma unroll
    for (int e = 0; e < 8; e++) {
        int k = kbase + e;
        int s = k >> 8, kk = k & 255;
        v8[e] = (__bf16)U[((g * 2 + s) * 256 + kk) * 256 + col];
    }
    *(bf16x8*)(BtP + (long)t * 8) = v8;
}

__global__ void leaf_kernel(const int* __restrict__ ids, const float* __restrict__ xg,
                            __bf16* __restrict__ h, __bf16* __restrict__ c) {
    int col = threadIdx.x;                 // 0..255
    int r0 = blockIdx.x * 32;              // 2048 blocks x 32 rows
    for (int r = r0; r < r0 + 32; r++) {
        int b = r >> 10, j = r & 1023;
        int id = ids[b * 2046 + 1022 + j];
        float x1 = xg[(64  + id) * 256 + col];
        float x2 = xg[(128 + id) * 256 + col];
        float x3 = xg[(192 + id) * 256 + col];
        float ig = sigf(x1);
        float og = sigf(x2);
        float ug = tanhfast(x3);
        float cv = ig * ug;
        float hv = og * tanhfast(cv);
        h[r * 256 + col] = (__bf16)hv;
        c[r * 256 + col] = (__bf16)cv;
    }
}

// Block = 512 thr = 8 waves x 64 rows; one ct (16 cols), all 5 gates.
__global__ __launch_bounds__(512, 2) void level_kernel(
    const __bf16* __restrict__ A, const __bf16* __restrict__ Cprev,
    const __bf16* __restrict__ BtP, const float* __restrict__ xg,
    const int* __restrict__ ids, __bf16* __restrict__ h_out,
    __bf16* __restrict__ c_out, float* __restrict__ rh_out, int lev, int M) {
    __shared__ __bf16 Blds[5 * 16 * 512];     // 81920 B -> 1 block/CU, 2 waves/SIMD
    const int tid  = threadIdx.x;
    const int wave = tid >> 6;
    const int lane = tid & 63;
    const int lr = lane & 15, q = lane >> 4;
    const int ct = blockIdx.y;
    const long wrow = (long)blockIdx.x * 512 + wave * 64;
    const bool active = (wrow < M);

    // ---- Stage B-slice -> LDS, fragment order (16B per thread-chunk). ----
    // Chunk c (0..5119): g = c/1024, r = c%1024 ;
    // src BtP[(g*16+ct)*8192 + r*8], dst Blds[g*8192 + r*8].
#pragma unroll
    for (int i = 0; i < 10; i++) {
        int c = tid + i * 512;
        int g = c >> 10;
        int r = c & 1023;
        i32x4 v = *(const i32x4*)(BtP + (long)(g * 16 + ct) * 8192 + r * 8);
        *(i32x4*)(&Blds[g * 8192 + r * 8]) = v;
    }

    // ---- A prefetch: steps 0 and 1 (2-deep). ----
    const __bf16* Ap = A + (wrow + lr) * 512 + q * 8;   // + mt*8192 + s*32
    bf16x8 af[3][4];
    if (active) {
#pragma unroll
        for (int mt = 0; mt < 4; mt++) {
            af[0][mt] = *(const bf16x8*)(Ap + mt * 8192);
            af[1][mt] = *(const bf16x8*)(Ap + mt * 8192 + 32);
        }
    }

    __syncthreads();

    // ---- Preload ids and children's c (latency hides under the K-loop). ----
    const int n = 1 << lev;
    const int gcol = ct * 16 + lr;
    int idv[4][4];
    __bf16 clv[4][4], crv[4][4];
    if (active) {
#pragma unroll
        for (int mt = 0; mt < 4; mt++)
#pragma unroll
            for (int v = 0; v < 4; v++) {
                long grow = wrow + mt * 16 + q * 4 + v;
                int b = (int)(grow >> lev);
                int j = (int)(grow & (n - 1));
                idv[mt][v] = ids[b * 2046 + (n - 2) + j];
                clv[mt][v] = Cprev[grow * 512 + gcol];
                crv[mt][v] = Cprev[grow * 512 + 256 + gcol];
            }
    }

    if (active) {
        f32x4 acc[5][4];
#pragma unroll
        for (int g2 = 0; g2 < 5; g2++)
#pragma unroll
            for (int mt = 0; mt < 4; mt++) acc[g2][mt] = (f32x4){0.f, 0.f, 0.f, 0.f};

        // B double-buffer from LDS (ds_read_b128, conflict-free: lane*16B).
        bf16x8 bb[2][5];
#pragma unroll
        for (int g2 = 0; g2 < 5; g2++)
            bb[0][g2] = *(const bf16x8*)(&Blds[g2 * 8192 + lane * 8]);

#pragma unroll
        for (int s = 0; s < 16; s++) {
            if (s + 1 < 16) {
#pragma unroll
                for (int g2 = 0; g2 < 5; g2++)
                    bb[(s + 1) & 1][g2] =
                        *(const bf16x8*)(&Blds[g2 * 8192 + (s + 1) * 512 + lane * 8]);
            }
            if (s + 2 < 16) {
#pragma unroll
                for (int mt = 0; mt < 4; mt++)
                    af[(s + 2) % 3][mt] =
                        *(const bf16x8*)(Ap + mt * 8192 + (s + 2) * 32);
            }
#pragma unroll
            for (int g2 = 0; g2 < 5; g2++)
#pragma unroll
                for (int mt = 0; mt < 4; mt++)
                    acc[g2][mt] = __builtin_amdgcn_mfma_f32_16x16x32_bf16(
                        af[s % 3][mt], bb[s & 1][g2], acc[g2][mt], 0, 0, 0);
        }

        // ---- Epilogue: in-register gate combine (v2's measured-clean pattern).
        // C layout: col = lane&15, row = q*4 + v (+16*mt).
#pragma unroll
        for (int mt = 0; mt < 4; mt++) {
#pragma unroll
            for (int v = 0; v < 4; v++) {
                long grow = wrow + mt * 16 + q * 4 + v;
                const float* xp = xg + idv[mt][v] * 256 + gcol;
                float fl = sigf(acc[0][mt][v] + xp[0]);          // f_l,f_r share xg[0]
                float fr = sigf(acc[1][mt][v] + xp[0]);
                float ig = sigf(acc[2][mt][v] + xp[16384]);      // xg[1]
                float og = sigf(acc[3][mt][v] + xp[32768]);      // xg[2]
                float ug = tanhfast(acc[4][mt][v] + xp[49152]);  // xg[3]
                float cv = ig * ug + fl * (float)clv[mt][v] + fr * (float)crv[mt][v];
                float hv = og * tanhfast(cv);
                h_out[grow * 256 + gcol] = (__bf16)hv;
                c_out[grow * 256 + gcol] = (__bf16)cv;
                if (rh_out) rh_out[grow * 256 + gcol] = hv;
            }
        }
    }
}

__global__ void scores_kernel(const float* __restrict__ rh, const float* __restrict__ Ws,
                              const float* __restrict__ bs, float* __restrict__ out) {
    int b = blockIdx.x;
    int t = threadIdx.x >> 6, lane = threadIdx.x & 63;
    float s = 0.f;
    for (int i = lane; i < 512; i += 64) s += rh[b * 512 + i] * Ws[i * 3 + t];
    for (int o = 32; o > 0; o >>= 1) s += __shfl_down(s, o);
    if (lane == 0) out[b * 3 + t] = s + bs[t];
}

extern "C" void kernel_launch(void* const* d_in, const int* in_sizes, int n_in,
                              void* d_out, int out_size, void* d_ws, size_t ws_size,
                              hipStream_t stream) {
    const int*   ids = (const int*)  d_in[0];
    const float* emb = (const float*)d_in[1];
    const float* W   = (const float*)d_in[2];
    const float* bW  = (const float*)d_in[3];
    const float* U   = (const float*)d_in[4];
    const float* Ws  = (const float*)d_in[5];
    const float* bs  = (const float*)d_in[6];
    float* out = (float*)d_out;   // [0:192) scores, [192:) root_hidden (64x512)

    char* ws = (char*)d_ws;
    float*  xg  = (float*)ws;                   //   262144 B : xg_table[4][64][256]
    __bf16* BtP = (__bf16*)(ws + 262144);       //  1310720 B : packed B fragments
    __bf16* h0  = (__bf16*)(ws + 1572864);      // 33554432 B : h ping (leaf-sized)
    __bf16* c0  = (__bf16*)(ws + 35127296);     // 33554432 B
    __bf16* h1  = (__bf16*)(ws + 68681728);     // 16777216 B : h pong
    __bf16* c1  = (__bf16*)(ws + 85458944);     // 16777216 B   (total 102236160 B)

    xg_prep<<<dim3(256), dim3(256), 0, stream>>>(emb, W, bW, xg);
    bt_prep<<<dim3(320), dim3(256), 0, stream>>>(U, BtP);
    leaf_kernel<<<dim3(2048), dim3(256), 0, stream>>>(ids, xg, h0, c0);

    __bf16* hb[2] = {h0, h1};
    __bf16* cb[2] = {c0, c1};
    int cur = 0;
    for (int lev = 9; lev >= 1; lev--) {
        int M = 64 << lev;                      // B * 2^lev rows
        int gx = (M + 511) / 512;
        float* rh = (lev == 1) ? (out + 192) : nullptr;
        level_kernel<<<dim3(gx, 16), dim3(512), 0, stream>>>(
            hb[cur], cb[cur], BtP, xg, ids, hb[1 - cur], cb[1 - cur], rh, lev, M);
        cur = 1 - cur;
    }
    scores_kernel<<<dim3(64), dim3(192), 0, stream>>>(out + 192, Ws, bs, out);
}